// Round 4
// baseline (688.361 us; speedup 1.0000x reference)
//
#include <hip/hip_runtime.h>

// ---------------------------------------------------------------------------
// GCN forward:  relu(x@W1+b1) -> gcnconv(Wc1) -> relu -> gcnconv(Wc2) -> relu
//               -> @W2 + b2
//
// R4: (a) gemm1 double-buffered LDS (1 barrier/chunk, prefetch overlap);
//     (b) conv intermediate t stored bf16 with dinv[row] pre-folded:
//         t'[r] = bf16(dinv[r] * (h@W)[r])
//         agg[c] = relu( dinv[c] * ( sum_e ew_e * t'[row_e] + t'[c] ) + b )
//         -> k_agg gathers 128 B/edge (8 slots x 16 B uint4), fp32 accum.
// ---------------------------------------------------------------------------

__device__ __forceinline__ unsigned bf16_rne(float f) {
    unsigned u = __float_as_uint(f);
    return (u + 0x7fffu + ((u >> 16) & 1u)) >> 16;   // finite inputs only
}

__device__ __forceinline__ void unpack8(uint4 p, float v[8]) {
    v[0] = __uint_as_float(p.x << 16); v[1] = __uint_as_float(p.x & 0xffff0000u);
    v[2] = __uint_as_float(p.y << 16); v[3] = __uint_as_float(p.y & 0xffff0000u);
    v[4] = __uint_as_float(p.z << 16); v[5] = __uint_as_float(p.z & 0xffff0000u);
    v[6] = __uint_as_float(p.w << 16); v[7] = __uint_as_float(p.w & 0xffff0000u);
}

// ============================= CSR build ===================================

__global__ __launch_bounds__(256) void k_zero_cnt(int* __restrict__ cnt, int n) {
    int i = blockIdx.x * 256 + threadIdx.x;
    if (i < n) cnt[i] = 0;
}

__global__ __launch_bounds__(256) void k_hist(const int* __restrict__ col,
                                              int* __restrict__ cnt,
                                              int* __restrict__ rank, int ne) {
    int i = blockIdx.x * 256 + threadIdx.x;
    if (i < ne) rank[i] = atomicAdd(&cnt[col[i]], 1);
}

__global__ __launch_bounds__(256) void k_scan1(const int* __restrict__ cnt,
                                               int* __restrict__ ptr,
                                               int* __restrict__ bsum, int n) {
    __shared__ int s[256];
    const int t = threadIdx.x;
    const int i = blockIdx.x * 256 + t;
    int v = (i < n) ? cnt[i] : 0;
    s[t] = v;
    __syncthreads();
#pragma unroll
    for (int off = 1; off < 256; off <<= 1) {
        int x = (t >= off) ? s[t - off] : 0;
        __syncthreads();
        s[t] += x;
        __syncthreads();
    }
    if (i < n) ptr[i] = s[t] - v;
    if (t == 255) bsum[blockIdx.x] = s[255];
}

__global__ __launch_bounds__(512) void k_scan2(int* __restrict__ bsum, int nb) {
    __shared__ int s[512];
    const int t = threadIdx.x;
    int v = (t < nb) ? bsum[t] : 0;
    s[t] = v;
    __syncthreads();
#pragma unroll
    for (int off = 1; off < 512; off <<= 1) {
        int x = (t >= off) ? s[t - off] : 0;
        __syncthreads();
        s[t] += x;
        __syncthreads();
    }
    if (t < nb) bsum[t] = s[t] - v;
}

__global__ __launch_bounds__(256) void k_scan3(int* __restrict__ ptr,
                                               const int* __restrict__ bsum,
                                               int n, int etot) {
    int i = blockIdx.x * 256 + threadIdx.x;
    if (i < n) ptr[i] = ptr[i] + bsum[i >> 8];
    if (i == 0) ptr[n] = etot;
}

__global__ __launch_bounds__(256) void k_scatter(const int* __restrict__ row,
                                                 const int* __restrict__ col,
                                                 const float* __restrict__ ew,
                                                 const int* __restrict__ ptr,
                                                 const int* __restrict__ rank,
                                                 int2* __restrict__ recs, int ne) {
    int i = blockIdx.x * 256 + threadIdx.x;
    if (i < ne) {
        int c = col[i];
        int pos = ptr[c] + rank[i];
        recs[pos] = make_int2(row[i], __float_as_int(ew[i]));
    }
}

__global__ __launch_bounds__(256) void k_csr_deg(const int* __restrict__ ptr,
                                                 const int2* __restrict__ recs,
                                                 float* __restrict__ dinv, int n) {
    int i = blockIdx.x * 256 + threadIdx.x;
    if (i < n) {
        int s = ptr[i], e = ptr[i + 1];
        float d = 1.0f;  // self-loop
        for (int j = s; j < e; ++j) d += __int_as_float(recs[j].y);
        dinv[i] = rsqrtf(d);
    }
}

// ============================= GEMM1 (double-buffered) =====================
// h = relu(x @ W1 + b1); x[N,256], W1[256,64]. 64x64 tile, BK=32, 8 chunks.
__global__ __launch_bounds__(256, 4) void k_gemm1(const float* __restrict__ x,
                                                  const float* __restrict__ W,
                                                  const float* __restrict__ bias,
                                                  float* __restrict__ h, int n) {
    __shared__ float xs[2][64 * 36];   // 64 rows x 32 k, stride 36
    __shared__ float ws[2][32 * 64];   // 32 k x 64 cols
    const int tid = threadIdx.x;
    const int row0 = blockIdx.x * 64;
    const int tx = tid & 15, ty = tid >> 4;
    // staging indices for x tile: 512 float4 total, 2 per thread
    const int r0 = tid >> 3;                 // row for f=tid
    const int c0 = (tid & 7) * 4;            // k-col
    const int r1 = (tid + 256) >> 3;
    const int c1 = ((tid + 256) & 7) * 4;
    float acc[4][4] = {};
    float4 rx0, rx1, rw0, rw1;

    // --- preload chunk 0 into regs ---
    {
        const float4* wsrc = (const float4*)W;          // k0 = 0
        rw0 = wsrc[tid];
        rw1 = wsrc[tid + 256];
        int rowa = row0 + r0, rowb = row0 + r1;
        rx0 = make_float4(0.f, 0.f, 0.f, 0.f);
        rx1 = make_float4(0.f, 0.f, 0.f, 0.f);
        if (rowa < n) rx0 = *(const float4*)(x + (size_t)rowa * 256 + c0);
        if (rowb < n) rx1 = *(const float4*)(x + (size_t)rowb * 256 + c1);
    }
    ((float4*)ws[0])[tid] = rw0;
    ((float4*)ws[0])[tid + 256] = rw1;
    *(float4*)(&xs[0][r0 * 36 + c0]) = rx0;
    *(float4*)(&xs[0][r1 * 36 + c1]) = rx1;
    __syncthreads();

    for (int kb = 0; kb < 8; ++kb) {
        const int cur = kb & 1;
        if (kb < 7) {
            const int k0 = (kb + 1) * 32;
            const float4* wsrc = (const float4*)(W + k0 * 64);
            rw0 = wsrc[tid];
            rw1 = wsrc[tid + 256];
            int rowa = row0 + r0, rowb = row0 + r1;
            rx0 = make_float4(0.f, 0.f, 0.f, 0.f);
            rx1 = make_float4(0.f, 0.f, 0.f, 0.f);
            if (rowa < n) rx0 = *(const float4*)(x + (size_t)rowa * 256 + k0 + c0);
            if (rowb < n) rx1 = *(const float4*)(x + (size_t)rowb * 256 + k0 + c1);
        }
#pragma unroll
        for (int kk = 0; kk < 32; kk += 4) {
            float4 a[4], b[4];
#pragma unroll
            for (int j = 0; j < 4; ++j)
                a[j] = *(const float4*)(&xs[cur][(ty * 4 + j) * 36 + kk]);
#pragma unroll
            for (int q = 0; q < 4; ++q)
                b[q] = *(const float4*)(&ws[cur][(kk + q) * 64 + tx * 4]);
#pragma unroll
            for (int j = 0; j < 4; ++j) {
                float aj[4] = {a[j].x, a[j].y, a[j].z, a[j].w};
#pragma unroll
                for (int q = 0; q < 4; ++q) {
                    acc[j][0] = fmaf(aj[q], b[q].x, acc[j][0]);
                    acc[j][1] = fmaf(aj[q], b[q].y, acc[j][1]);
                    acc[j][2] = fmaf(aj[q], b[q].z, acc[j][2]);
                    acc[j][3] = fmaf(aj[q], b[q].w, acc[j][3]);
                }
            }
        }
        if (kb < 7) {
            const int nxt = cur ^ 1;
            ((float4*)ws[nxt])[tid] = rw0;
            ((float4*)ws[nxt])[tid + 256] = rw1;
            *(float4*)(&xs[nxt][r0 * 36 + c0]) = rx0;
            *(float4*)(&xs[nxt][r1 * 36 + c1]) = rx1;
            __syncthreads();
        }
    }

    float4 bb = *(const float4*)(bias + tx * 4);
#pragma unroll
    for (int j = 0; j < 4; ++j) {
        int row = row0 + ty * 4 + j;
        if (row < n) {
            float4 o;
            o.x = fmaxf(acc[j][0] + bb.x, 0.f);
            o.y = fmaxf(acc[j][1] + bb.y, 0.f);
            o.z = fmaxf(acc[j][2] + bb.z, 0.f);
            o.w = fmaxf(acc[j][3] + bb.w, 0.f);
            *(float4*)(h + (size_t)row * 64 + tx * 4) = o;
        }
    }
}

// ============================= Conv dense part =============================
// t'[r] = bf16( dinv[r] * (hin @ W)[r] )   -- bf16, 128 B per row
__global__ __launch_bounds__(256) void k_conv(const float* __restrict__ hin,
                                              const float* __restrict__ W,
                                              const float* __restrict__ dinv,
                                              unsigned* __restrict__ tb,  // bf16 x2 per uint
                                              int n) {
    __shared__ float xs[64 * 68];
    __shared__ float ws[64 * 64];
    const int tid = threadIdx.x;
    const int row0 = blockIdx.x * 64;
    const int tx = tid & 15, ty = tid >> 4;

    {
        const float4* src = (const float4*)W;
        float4* dst = (float4*)ws;
#pragma unroll
        for (int i = 0; i < 4; ++i) dst[tid + i * 256] = src[tid + i * 256];
    }
#pragma unroll
    for (int i = 0; i < 4; ++i) {
        int f = tid + i * 256;
        int r = f >> 4;
        int c = (f & 15) * 4;
        int row = row0 + r;
        float4 v = make_float4(0.f, 0.f, 0.f, 0.f);
        if (row < n) v = *(const float4*)(hin + (size_t)row * 64 + c);
        *(float4*)(xs + r * 68 + c) = v;
    }
    __syncthreads();

    float acc[4][4] = {};
#pragma unroll
    for (int kk = 0; kk < 64; kk += 4) {
        float4 a[4], b[4];
#pragma unroll
        for (int j = 0; j < 4; ++j)
            a[j] = *(const float4*)(xs + (ty * 4 + j) * 68 + kk);
#pragma unroll
        for (int q = 0; q < 4; ++q)
            b[q] = *(const float4*)(ws + (kk + q) * 64 + tx * 4);
#pragma unroll
        for (int j = 0; j < 4; ++j) {
            float aj[4] = {a[j].x, a[j].y, a[j].z, a[j].w};
#pragma unroll
            for (int q = 0; q < 4; ++q) {
                acc[j][0] = fmaf(aj[q], b[q].x, acc[j][0]);
                acc[j][1] = fmaf(aj[q], b[q].y, acc[j][1]);
                acc[j][2] = fmaf(aj[q], b[q].z, acc[j][2]);
                acc[j][3] = fmaf(aj[q], b[q].w, acc[j][3]);
            }
        }
    }
#pragma unroll
    for (int j = 0; j < 4; ++j) {
        int row = row0 + ty * 4 + j;
        if (row < n) {
            float dv = dinv[row];
            uint2 w;
            w.x = bf16_rne(dv * acc[j][0]) | (bf16_rne(dv * acc[j][1]) << 16);
            w.y = bf16_rne(dv * acc[j][2]) | (bf16_rne(dv * acc[j][3]) << 16);
            *(uint2*)(tb + (size_t)row * 32 + tx * 2) = w;
        }
    }
}

// ============================= CSR aggregation =============================
// One wave per node c. 8 edge slots (grp=lane>>3), lane handles 8 bf16 feats
// (f = lane&7, one uint4 = 16 B gather). fp32 accumulate, shfl-reduce.
__global__ __launch_bounds__(256) void k_agg(const int* __restrict__ ptr,
                                             const int2* __restrict__ recs,
                                             const float* __restrict__ dinv,
                                             const float* __restrict__ bias,
                                             const uint4* __restrict__ t4,  // bf16 rows, 8 uint4/row
                                             float4* __restrict__ agg4, int n) {
    const int lane = threadIdx.x & 63;
    const int c = blockIdx.x * 4 + (threadIdx.x >> 6);
    if (c >= n) return;
    const int grp = lane >> 3;
    const int f = lane & 7;

    float acc[8] = {};
    if (grp == 0) {  // self term: + t'[c]
        float v[8];
        unpack8(t4[(size_t)c * 8 + f], v);
#pragma unroll
        for (int i = 0; i < 8; ++i) acc[i] = v[i];
    }

    const int eEnd = ptr[c + 1];
    int e = ptr[c] + grp;
    int2 rec = (e < eEnd) ? recs[e] : make_int2(0, 0);
    while (e < eEnd) {
        int2 cur = rec;
        e += 8;
        if (e < eEnd) rec = recs[e];
        uint4 p = t4[(size_t)cur.x * 8 + f];
        float w = __int_as_float(cur.y);
        float v[8];
        unpack8(p, v);
#pragma unroll
        for (int i = 0; i < 8; ++i) acc[i] = fmaf(w, v[i], acc[i]);
    }

#pragma unroll
    for (int off = 8; off < 64; off <<= 1) {
#pragma unroll
        for (int i = 0; i < 8; ++i) acc[i] += __shfl_xor(acc[i], off, 64);
    }

    if (grp == 0) {
        const float wc = dinv[c];
        float4 b0 = ((const float4*)bias)[f * 2];
        float4 b1 = ((const float4*)bias)[f * 2 + 1];
        float4 o0, o1;
        o0.x = fmaxf(fmaf(wc, acc[0], b0.x), 0.f);
        o0.y = fmaxf(fmaf(wc, acc[1], b0.y), 0.f);
        o0.z = fmaxf(fmaf(wc, acc[2], b0.z), 0.f);
        o0.w = fmaxf(fmaf(wc, acc[3], b0.w), 0.f);
        o1.x = fmaxf(fmaf(wc, acc[4], b1.x), 0.f);
        o1.y = fmaxf(fmaf(wc, acc[5], b1.y), 0.f);
        o1.z = fmaxf(fmaf(wc, acc[6], b1.z), 0.f);
        o1.w = fmaxf(fmaf(wc, acc[7], b1.w), 0.f);
        agg4[(size_t)c * 16 + f * 2] = o0;
        agg4[(size_t)c * 16 + f * 2 + 1] = o1;
    }
}

// ============================= Final GEMM ==================================
// out = hin @ W2 + b2;  hin already relu'd. W2[64,40]
__global__ __launch_bounds__(256) void k_final(const float* __restrict__ hin,
                                               const float* __restrict__ W,
                                               const float* __restrict__ bias,
                                               float* __restrict__ out, int n) {
    __shared__ float xs[64 * 68];
    __shared__ float ws[64 * 40];
    const int tid = threadIdx.x;
    const int row0 = blockIdx.x * 64;

    for (int i = tid; i < 640; i += 256)
        ((float4*)ws)[i] = ((const float4*)W)[i];
#pragma unroll
    for (int i = 0; i < 4; ++i) {
        int f = tid + i * 256;
        int r = f >> 4;
        int c = (f & 15) * 4;
        int row = row0 + r;
        float4 v = make_float4(0.f, 0.f, 0.f, 0.f);
        if (row < n) v = *(const float4*)(hin + (size_t)row * 64 + c);
        *(float4*)(xs + r * 68 + c) = v;
    }
    __syncthreads();

    const int tx = tid & 15, ty = tid >> 4;
    if (tx < 10) {
        float acc[4][4] = {};
#pragma unroll
        for (int kk = 0; kk < 64; kk += 4) {
            float4 a[4], b[4];
#pragma unroll
            for (int j = 0; j < 4; ++j)
                a[j] = *(const float4*)(xs + (ty * 4 + j) * 68 + kk);
#pragma unroll
            for (int q = 0; q < 4; ++q)
                b[q] = *(const float4*)(ws + (kk + q) * 40 + tx * 4);
#pragma unroll
            for (int j = 0; j < 4; ++j) {
                float aj[4] = {a[j].x, a[j].y, a[j].z, a[j].w};
#pragma unroll
                for (int q = 0; q < 4; ++q) {
                    acc[j][0] = fmaf(aj[q], b[q].x, acc[j][0]);
                    acc[j][1] = fmaf(aj[q], b[q].y, acc[j][1]);
                    acc[j][2] = fmaf(aj[q], b[q].z, acc[j][2]);
                    acc[j][3] = fmaf(aj[q], b[q].w, acc[j][3]);
                }
            }
        }
        float4 bb = *(const float4*)(bias + tx * 4);
#pragma unroll
        for (int j = 0; j < 4; ++j) {
            int row = row0 + ty * 4 + j;
            if (row < n) {
                float4 o = make_float4(acc[j][0] + bb.x, acc[j][1] + bb.y,
                                       acc[j][2] + bb.z, acc[j][3] + bb.w);
                *(float4*)(out + (size_t)row * 40 + tx * 4) = o;
            }
        }
    }
}

extern "C" void kernel_launch(void* const* d_in, const int* in_sizes, int n_in,
                              void* d_out, int out_size, void* d_ws, size_t ws_size,
                              hipStream_t stream) {
    const float* x   = (const float*)d_in[0];
    const int*   ei  = (const int*)d_in[1];
    const float* ew  = (const float*)d_in[2];
    const float* W1  = (const float*)d_in[3];
    const float* b1  = (const float*)d_in[4];
    const float* Wc1 = (const float*)d_in[5];
    const float* bc1 = (const float*)d_in[6];
    const float* Wc2 = (const float*)d_in[7];
    const float* bc2 = (const float*)d_in[8];
    const float* W2  = (const float*)d_in[9];
    const float* b2  = (const float*)d_in[10];
    float* out = (float*)d_out;

    const int N = in_sizes[0] / 256;
    const int E = in_sizes[2];
    const int* row = ei;
    const int* col = ei + E;

    // workspace layout:
    // recs[E int2] | bufA[64N f] | bufB[64N f] | dinv[N f] | cnt[N i] | ptr[N+1 i] | bsum[512 i]
    // rank[E] aliases head of bufA (dead before gemm1 writes h1).
    // bufB doubles as bf16 t' (uses first 32N floats of it).
    int2*  recs = (int2*)d_ws;
    float* bufA = (float*)(recs + E);
    float* bufB = bufA + (size_t)N * 64;
    float* dinv = bufB + (size_t)N * 64;
    int*   cnt  = (int*)(dinv + N);
    int*   ptr  = cnt + N;
    int*   bsum = ptr + N + 1;
    int*   rank = (int*)bufA;
    unsigned* tb = (unsigned*)bufB;   // bf16 t', 32 uints per row

    const int gN = (N + 255) / 256;
    const int gE = (E + 255) / 256;
    const int gG = (N + 63) / 64;
    const int gA = (N + 3) / 4;

    // --- CSR build (shared by both convs) ---
    k_zero_cnt<<<gN, 256, 0, stream>>>(cnt, N);
    k_hist<<<gE, 256, 0, stream>>>(col, cnt, rank, E);
    k_scan1<<<gN, 256, 0, stream>>>(cnt, ptr, bsum, N);
    k_scan2<<<1, 512, 0, stream>>>(bsum, gN);
    k_scan3<<<gN, 256, 0, stream>>>(ptr, bsum, N, E);
    k_scatter<<<gE, 256, 0, stream>>>(row, col, ew, ptr, rank, recs, E);
    k_csr_deg<<<gN, 256, 0, stream>>>(ptr, recs, dinv, N);

    // --- layer 1: h1 = relu(x@W1+b1) -> bufA ---
    k_gemm1<<<gG, 256, 0, stream>>>(x, W1, b1, bufA, N);

    // --- conv1: t' = bf16(dinv.(h1@Wc1)) -> tb; agg1 -> bufA ---
    k_conv<<<gG, 256, 0, stream>>>(bufA, Wc1, dinv, tb, N);
    k_agg<<<gA, 256, 0, stream>>>(ptr, recs, dinv, bc1, (const uint4*)tb,
                                  (float4*)bufA, N);

    // --- conv2: t' = bf16(dinv.(agg1@Wc2)) -> tb; agg2 -> bufA ---
    k_conv<<<gG, 256, 0, stream>>>(bufA, Wc2, dinv, tb, N);
    k_agg<<<gA, 256, 0, stream>>>(ptr, recs, dinv, bc2, (const uint4*)tb,
                                  (float4*)bufA, N);

    // --- out = agg2 @ W2 + b2 ---
    k_final<<<gG, 256, 0, stream>>>(bufA, W2, b2, out, N);
}

// Round 5
// 578.674 us; speedup vs baseline: 1.1896x; 1.1896x over previous
//
#include <hip/hip_runtime.h>

// ---------------------------------------------------------------------------
// GCN forward:  relu(x@W1+b1) -> gcnconv(Wc1) -> relu -> gcnconv(Wc2) -> relu
//               -> @W2 + b2
//
// R5: gemm1 = R3 single-LDS-buffer structure + register prefetch pipeline
//     (R4's double-buffer + __launch_bounds__(256,4) spilled to scratch:
//      WRITE_SIZE 25->245 MB. Do NOT re-add a min-occupancy bound here.)
//     bf16 t' with dinv[row] pre-folded kept from R4 (absmax 9.8e-4, passes).
// ---------------------------------------------------------------------------

__device__ __forceinline__ unsigned bf16_rne(float f) {
    unsigned u = __float_as_uint(f);
    return (u + 0x7fffu + ((u >> 16) & 1u)) >> 16;   // finite inputs only
}

__device__ __forceinline__ void unpack8(uint4 p, float v[8]) {
    v[0] = __uint_as_float(p.x << 16); v[1] = __uint_as_float(p.x & 0xffff0000u);
    v[2] = __uint_as_float(p.y << 16); v[3] = __uint_as_float(p.y & 0xffff0000u);
    v[4] = __uint_as_float(p.z << 16); v[5] = __uint_as_float(p.z & 0xffff0000u);
    v[6] = __uint_as_float(p.w << 16); v[7] = __uint_as_float(p.w & 0xffff0000u);
}

// ============================= CSR build ===================================

__global__ __launch_bounds__(256) void k_zero_cnt(int* __restrict__ cnt, int n) {
    int i = blockIdx.x * 256 + threadIdx.x;
    if (i < n) cnt[i] = 0;
}

__global__ __launch_bounds__(256) void k_hist(const int* __restrict__ col,
                                              int* __restrict__ cnt,
                                              int* __restrict__ rank, int ne) {
    int i = blockIdx.x * 256 + threadIdx.x;
    if (i < ne) rank[i] = atomicAdd(&cnt[col[i]], 1);
}

__global__ __launch_bounds__(256) void k_scan1(const int* __restrict__ cnt,
                                               int* __restrict__ ptr,
                                               int* __restrict__ bsum, int n) {
    __shared__ int s[256];
    const int t = threadIdx.x;
    const int i = blockIdx.x * 256 + t;
    int v = (i < n) ? cnt[i] : 0;
    s[t] = v;
    __syncthreads();
#pragma unroll
    for (int off = 1; off < 256; off <<= 1) {
        int x = (t >= off) ? s[t - off] : 0;
        __syncthreads();
        s[t] += x;
        __syncthreads();
    }
    if (i < n) ptr[i] = s[t] - v;
    if (t == 255) bsum[blockIdx.x] = s[255];
}

__global__ __launch_bounds__(512) void k_scan2(int* __restrict__ bsum, int nb) {
    __shared__ int s[512];
    const int t = threadIdx.x;
    int v = (t < nb) ? bsum[t] : 0;
    s[t] = v;
    __syncthreads();
#pragma unroll
    for (int off = 1; off < 512; off <<= 1) {
        int x = (t >= off) ? s[t - off] : 0;
        __syncthreads();
        s[t] += x;
        __syncthreads();
    }
    if (t < nb) bsum[t] = s[t] - v;
}

__global__ __launch_bounds__(256) void k_scan3(int* __restrict__ ptr,
                                               const int* __restrict__ bsum,
                                               int n, int etot) {
    int i = blockIdx.x * 256 + threadIdx.x;
    if (i < n) ptr[i] = ptr[i] + bsum[i >> 8];
    if (i == 0) ptr[n] = etot;
}

__global__ __launch_bounds__(256) void k_scatter(const int* __restrict__ row,
                                                 const int* __restrict__ col,
                                                 const float* __restrict__ ew,
                                                 const int* __restrict__ ptr,
                                                 const int* __restrict__ rank,
                                                 int2* __restrict__ recs, int ne) {
    int i = blockIdx.x * 256 + threadIdx.x;
    if (i < ne) {
        int c = col[i];
        int pos = ptr[c] + rank[i];
        recs[pos] = make_int2(row[i], __float_as_int(ew[i]));
    }
}

__global__ __launch_bounds__(256) void k_csr_deg(const int* __restrict__ ptr,
                                                 const int2* __restrict__ recs,
                                                 float* __restrict__ dinv, int n) {
    int i = blockIdx.x * 256 + threadIdx.x;
    if (i < n) {
        int s = ptr[i], e = ptr[i + 1];
        float d = 1.0f;  // self-loop
        for (int j = s; j < e; ++j) d += __int_as_float(recs[j].y);
        dinv[i] = rsqrtf(d);
    }
}

// ============================= GEMM1 (reg-prefetch pipeline) ===============
// h = relu(x @ W1 + b1); x[N,256], W1[256,64]. 64x64 tile, BK=64, 4 chunks.
// Single LDS buffer; next chunk prefetched into registers during compute.
__global__ __launch_bounds__(256) void k_gemm1(const float* __restrict__ x,
                                               const float* __restrict__ W,
                                               const float* __restrict__ bias,
                                               float* __restrict__ h, int n) {
    __shared__ float xs[64 * 68];
    __shared__ float ws[64 * 64];
    const int tid = threadIdx.x;
    const int row0 = blockIdx.x * 64;
    const int tx = tid & 15, ty = tid >> 4;
    float acc[4][4] = {};
    float4 pw[4], px[4];

    // prefetch chunk 0 into registers
    {
        const float4* wsrc = (const float4*)W;
#pragma unroll
        for (int i = 0; i < 4; ++i) pw[i] = wsrc[tid + i * 256];
#pragma unroll
        for (int i = 0; i < 4; ++i) {
            int f = tid + i * 256;
            int r = f >> 4;
            int c = (f & 15) * 4;
            int row = row0 + r;
            px[i] = make_float4(0.f, 0.f, 0.f, 0.f);
            if (row < n) px[i] = *(const float4*)(x + (size_t)row * 256 + c);
        }
    }

    for (int kb = 0; kb < 4; ++kb) {
        // store staged registers -> LDS
        {
            float4* dst = (float4*)ws;
#pragma unroll
            for (int i = 0; i < 4; ++i) dst[tid + i * 256] = pw[i];
#pragma unroll
            for (int i = 0; i < 4; ++i) {
                int f = tid + i * 256;
                int r = f >> 4;
                int c = (f & 15) * 4;
                *(float4*)(xs + r * 68 + c) = px[i];
            }
        }
        __syncthreads();
        // prefetch chunk kb+1 (overlaps with compute below)
        if (kb < 3) {
            const int k0 = (kb + 1) * 64;
            const float4* wsrc = (const float4*)(W + k0 * 64);
#pragma unroll
            for (int i = 0; i < 4; ++i) pw[i] = wsrc[tid + i * 256];
#pragma unroll
            for (int i = 0; i < 4; ++i) {
                int f = tid + i * 256;
                int r = f >> 4;
                int c = (f & 15) * 4;
                int row = row0 + r;
                px[i] = make_float4(0.f, 0.f, 0.f, 0.f);
                if (row < n) px[i] = *(const float4*)(x + (size_t)row * 256 + k0 + c);
            }
        }
        // compute chunk kb from LDS
#pragma unroll
        for (int kk = 0; kk < 64; kk += 4) {
            float4 a[4], b[4];
#pragma unroll
            for (int j = 0; j < 4; ++j)
                a[j] = *(const float4*)(xs + (ty * 4 + j) * 68 + kk);
#pragma unroll
            for (int q = 0; q < 4; ++q)
                b[q] = *(const float4*)(ws + (kk + q) * 64 + tx * 4);
#pragma unroll
            for (int j = 0; j < 4; ++j) {
                float aj[4] = {a[j].x, a[j].y, a[j].z, a[j].w};
#pragma unroll
                for (int q = 0; q < 4; ++q) {
                    acc[j][0] = fmaf(aj[q], b[q].x, acc[j][0]);
                    acc[j][1] = fmaf(aj[q], b[q].y, acc[j][1]);
                    acc[j][2] = fmaf(aj[q], b[q].z, acc[j][2]);
                    acc[j][3] = fmaf(aj[q], b[q].w, acc[j][3]);
                }
            }
        }
        __syncthreads();   // all reads done before next store
    }

    float4 bb = *(const float4*)(bias + tx * 4);
#pragma unroll
    for (int j = 0; j < 4; ++j) {
        int row = row0 + ty * 4 + j;
        if (row < n) {
            float4 o;
            o.x = fmaxf(acc[j][0] + bb.x, 0.f);
            o.y = fmaxf(acc[j][1] + bb.y, 0.f);
            o.z = fmaxf(acc[j][2] + bb.z, 0.f);
            o.w = fmaxf(acc[j][3] + bb.w, 0.f);
            *(float4*)(h + (size_t)row * 64 + tx * 4) = o;
        }
    }
}

// ============================= Conv dense part =============================
// t'[r] = bf16( dinv[r] * (hin @ W)[r] )   -- bf16, 128 B per row
__global__ __launch_bounds__(256) void k_conv(const float* __restrict__ hin,
                                              const float* __restrict__ W,
                                              const float* __restrict__ dinv,
                                              unsigned* __restrict__ tb,  // bf16 x2 per uint
                                              int n) {
    __shared__ float xs[64 * 68];
    __shared__ float ws[64 * 64];
    const int tid = threadIdx.x;
    const int row0 = blockIdx.x * 64;
    const int tx = tid & 15, ty = tid >> 4;

    {
        const float4* src = (const float4*)W;
        float4* dst = (float4*)ws;
#pragma unroll
        for (int i = 0; i < 4; ++i) dst[tid + i * 256] = src[tid + i * 256];
    }
#pragma unroll
    for (int i = 0; i < 4; ++i) {
        int f = tid + i * 256;
        int r = f >> 4;
        int c = (f & 15) * 4;
        int row = row0 + r;
        float4 v = make_float4(0.f, 0.f, 0.f, 0.f);
        if (row < n) v = *(const float4*)(hin + (size_t)row * 64 + c);
        *(float4*)(xs + r * 68 + c) = v;
    }
    __syncthreads();

    float acc[4][4] = {};
#pragma unroll
    for (int kk = 0; kk < 64; kk += 4) {
        float4 a[4], b[4];
#pragma unroll
        for (int j = 0; j < 4; ++j)
            a[j] = *(const float4*)(xs + (ty * 4 + j) * 68 + kk);
#pragma unroll
        for (int q = 0; q < 4; ++q)
            b[q] = *(const float4*)(ws + (kk + q) * 64 + tx * 4);
#pragma unroll
        for (int j = 0; j < 4; ++j) {
            float aj[4] = {a[j].x, a[j].y, a[j].z, a[j].w};
#pragma unroll
            for (int q = 0; q < 4; ++q) {
                acc[j][0] = fmaf(aj[q], b[q].x, acc[j][0]);
                acc[j][1] = fmaf(aj[q], b[q].y, acc[j][1]);
                acc[j][2] = fmaf(aj[q], b[q].z, acc[j][2]);
                acc[j][3] = fmaf(aj[q], b[q].w, acc[j][3]);
            }
        }
    }
#pragma unroll
    for (int j = 0; j < 4; ++j) {
        int row = row0 + ty * 4 + j;
        if (row < n) {
            float dv = dinv[row];
            uint2 w;
            w.x = bf16_rne(dv * acc[j][0]) | (bf16_rne(dv * acc[j][1]) << 16);
            w.y = bf16_rne(dv * acc[j][2]) | (bf16_rne(dv * acc[j][3]) << 16);
            *(uint2*)(tb + (size_t)row * 32 + tx * 2) = w;
        }
    }
}

// ============================= CSR aggregation =============================
// One wave per node c. 8 edge slots (grp=lane>>3), lane handles 8 bf16 feats
// (f = lane&7, one uint4 = 16 B gather). fp32 accumulate, shfl-reduce.
__global__ __launch_bounds__(256) void k_agg(const int* __restrict__ ptr,
                                             const int2* __restrict__ recs,
                                             const float* __restrict__ dinv,
                                             const float* __restrict__ bias,
                                             const uint4* __restrict__ t4,  // bf16 rows, 8 uint4/row
                                             float4* __restrict__ agg4, int n) {
    const int lane = threadIdx.x & 63;
    const int c = blockIdx.x * 4 + (threadIdx.x >> 6);
    if (c >= n) return;
    const int grp = lane >> 3;
    const int f = lane & 7;

    float acc[8] = {};
    if (grp == 0) {  // self term: + t'[c]
        float v[8];
        unpack8(t4[(size_t)c * 8 + f], v);
#pragma unroll
        for (int i = 0; i < 8; ++i) acc[i] = v[i];
    }

    const int eEnd = ptr[c + 1];
    int e = ptr[c] + grp;
    int2 rec = (e < eEnd) ? recs[e] : make_int2(0, 0);
    while (e < eEnd) {
        int2 cur = rec;
        e += 8;
        if (e < eEnd) rec = recs[e];
        uint4 p = t4[(size_t)cur.x * 8 + f];
        float w = __int_as_float(cur.y);
        float v[8];
        unpack8(p, v);
#pragma unroll
        for (int i = 0; i < 8; ++i) acc[i] = fmaf(w, v[i], acc[i]);
    }

#pragma unroll
    for (int off = 8; off < 64; off <<= 1) {
#pragma unroll
        for (int i = 0; i < 8; ++i) acc[i] += __shfl_xor(acc[i], off, 64);
    }

    if (grp == 0) {
        const float wc = dinv[c];
        float4 b0 = ((const float4*)bias)[f * 2];
        float4 b1 = ((const float4*)bias)[f * 2 + 1];
        float4 o0, o1;
        o0.x = fmaxf(fmaf(wc, acc[0], b0.x), 0.f);
        o0.y = fmaxf(fmaf(wc, acc[1], b0.y), 0.f);
        o0.z = fmaxf(fmaf(wc, acc[2], b0.z), 0.f);
        o0.w = fmaxf(fmaf(wc, acc[3], b0.w), 0.f);
        o1.x = fmaxf(fmaf(wc, acc[4], b1.x), 0.f);
        o1.y = fmaxf(fmaf(wc, acc[5], b1.y), 0.f);
        o1.z = fmaxf(fmaf(wc, acc[6], b1.z), 0.f);
        o1.w = fmaxf(fmaf(wc, acc[7], b1.w), 0.f);
        agg4[(size_t)c * 16 + f * 2] = o0;
        agg4[(size_t)c * 16 + f * 2 + 1] = o1;
    }
}

// ============================= Final GEMM ==================================
// out = hin @ W2 + b2;  hin already relu'd. W2[64,40]
__global__ __launch_bounds__(256) void k_final(const float* __restrict__ hin,
                                               const float* __restrict__ W,
                                               const float* __restrict__ bias,
                                               float* __restrict__ out, int n) {
    __shared__ float xs[64 * 68];
    __shared__ float ws[64 * 40];
    const int tid = threadIdx.x;
    const int row0 = blockIdx.x * 64;

    for (int i = tid; i < 640; i += 256)
        ((float4*)ws)[i] = ((const float4*)W)[i];
#pragma unroll
    for (int i = 0; i < 4; ++i) {
        int f = tid + i * 256;
        int r = f >> 4;
        int c = (f & 15) * 4;
        int row = row0 + r;
        float4 v = make_float4(0.f, 0.f, 0.f, 0.f);
        if (row < n) v = *(const float4*)(hin + (size_t)row * 64 + c);
        *(float4*)(xs + r * 68 + c) = v;
    }
    __syncthreads();

    const int tx = tid & 15, ty = tid >> 4;
    if (tx < 10) {
        float acc[4][4] = {};
#pragma unroll
        for (int kk = 0; kk < 64; kk += 4) {
            float4 a[4], b[4];
#pragma unroll
            for (int j = 0; j < 4; ++j)
                a[j] = *(const float4*)(xs + (ty * 4 + j) * 68 + kk);
#pragma unroll
            for (int q = 0; q < 4; ++q)
                b[q] = *(const float4*)(ws + (kk + q) * 40 + tx * 4);
#pragma unroll
            for (int j = 0; j < 4; ++j) {
                float aj[4] = {a[j].x, a[j].y, a[j].z, a[j].w};
#pragma unroll
                for (int q = 0; q < 4; ++q) {
                    acc[j][0] = fmaf(aj[q], b[q].x, acc[j][0]);
                    acc[j][1] = fmaf(aj[q], b[q].y, acc[j][1]);
                    acc[j][2] = fmaf(aj[q], b[q].z, acc[j][2]);
                    acc[j][3] = fmaf(aj[q], b[q].w, acc[j][3]);
                }
            }
        }
        float4 bb = *(const float4*)(bias + tx * 4);
#pragma unroll
        for (int j = 0; j < 4; ++j) {
            int row = row0 + ty * 4 + j;
            if (row < n) {
                float4 o = make_float4(acc[j][0] + bb.x, acc[j][1] + bb.y,
                                       acc[j][2] + bb.z, acc[j][3] + bb.w);
                *(float4*)(out + (size_t)row * 40 + tx * 4) = o;
            }
        }
    }
}

extern "C" void kernel_launch(void* const* d_in, const int* in_sizes, int n_in,
                              void* d_out, int out_size, void* d_ws, size_t ws_size,
                              hipStream_t stream) {
    const float* x   = (const float*)d_in[0];
    const int*   ei  = (const int*)d_in[1];
    const float* ew  = (const float*)d_in[2];
    const float* W1  = (const float*)d_in[3];
    const float* b1  = (const float*)d_in[4];
    const float* Wc1 = (const float*)d_in[5];
    const float* bc1 = (const float*)d_in[6];
    const float* Wc2 = (const float*)d_in[7];
    const float* bc2 = (const float*)d_in[8];
    const float* W2  = (const float*)d_in[9];
    const float* b2  = (const float*)d_in[10];
    float* out = (float*)d_out;

    const int N = in_sizes[0] / 256;
    const int E = in_sizes[2];
    const int* row = ei;
    const int* col = ei + E;

    // workspace layout:
    // recs[E int2] | bufA[64N f] | bufB[64N f] | dinv[N f] | cnt[N i] | ptr[N+1 i] | bsum[512 i]
    // rank[E] aliases head of bufA (dead before gemm1 writes h1).
    // bufB doubles as bf16 t' (uses first 32N floats of it).
    int2*  recs = (int2*)d_ws;
    float* bufA = (float*)(recs + E);
    float* bufB = bufA + (size_t)N * 64;
    float* dinv = bufB + (size_t)N * 64;
    int*   cnt  = (int*)(dinv + N);
    int*   ptr  = cnt + N;
    int*   bsum = ptr + N + 1;
    int*   rank = (int*)bufA;
    unsigned* tb = (unsigned*)bufB;   // bf16 t', 32 uints per row

    const int gN = (N + 255) / 256;
    const int gE = (E + 255) / 256;
    const int gG = (N + 63) / 64;
    const int gA = (N + 3) / 4;

    // --- CSR build (shared by both convs) ---
    k_zero_cnt<<<gN, 256, 0, stream>>>(cnt, N);
    k_hist<<<gE, 256, 0, stream>>>(col, cnt, rank, E);
    k_scan1<<<gN, 256, 0, stream>>>(cnt, ptr, bsum, N);
    k_scan2<<<1, 512, 0, stream>>>(bsum, gN);
    k_scan3<<<gN, 256, 0, stream>>>(ptr, bsum, N, E);
    k_scatter<<<gE, 256, 0, stream>>>(row, col, ew, ptr, rank, recs, E);
    k_csr_deg<<<gN, 256, 0, stream>>>(ptr, recs, dinv, N);

    // --- layer 1: h1 = relu(x@W1+b1) -> bufA ---
    k_gemm1<<<gG, 256, 0, stream>>>(x, W1, b1, bufA, N);

    // --- conv1: t' = bf16(dinv.(h1@Wc1)) -> tb; agg1 -> bufA ---
    k_conv<<<gG, 256, 0, stream>>>(bufA, Wc1, dinv, tb, N);
    k_agg<<<gA, 256, 0, stream>>>(ptr, recs, dinv, bc1, (const uint4*)tb,
                                  (float4*)bufA, N);

    // --- conv2: t' = bf16(dinv.(agg1@Wc2)) -> tb; agg2 -> bufA ---
    k_conv<<<gG, 256, 0, stream>>>(bufA, Wc2, dinv, tb, N);
    k_agg<<<gA, 256, 0, stream>>>(ptr, recs, dinv, bc2, (const uint4*)tb,
                                  (float4*)bufA, N);

    // --- out = agg2 @ W2 + b2 ---
    k_final<<<gG, 256, 0, stream>>>(bufA, W2, b2, out, N);
}